// Round 1
// baseline (300.294 us; speedup 1.0000x reference)
//
#include <hip/hip_runtime.h>
#include <stdint.h>

// Problem constants
#define NB   32
#define NCH  256
#define NPIX 3136      // 56*56
#define PH   58        // padded width/height (56+2)
#define PPIX 3364      // 58*58

typedef __bf16 bf16x8 __attribute__((ext_vector_type(8)));
typedef float  f32x4  __attribute__((ext_vector_type(4)));

__device__ __forceinline__ unsigned short f2bf(float f) {
  unsigned int u = __float_as_uint(f);
  u += 0x7fff + ((u >> 16) & 1);           // RNE
  return (unsigned short)(u >> 16);
}
__device__ __forceinline__ float bf2f(unsigned int us) {
  return __uint_as_float(us << 16);
}

// async global->LDS, 16B per lane. LDS ptr must be wave-uniform; HW adds lane*16.
__device__ __forceinline__ void gload_lds16(const void* g, void* l) {
  __builtin_amdgcn_global_load_lds(
      (const __attribute__((address_space(1))) unsigned int*)(uintptr_t)g,
      (__attribute__((address_space(3))) unsigned int*)(unsigned int)(uintptr_t)l,
      16, 0, 0);
}

// ---------------- zero the padded borders of xT ----------------
__global__ __launch_bounds__(128) void zero_border(unsigned short* __restrict__ xT) {
  int b = blockIdx.y;
  int idx = blockIdx.x;            // 0..227 border pixel positions
  int row;
  if (idx < 58)       row = idx;                       // ph = 0
  else if (idx < 116) row = 57 * 58 + (idx - 58);      // ph = 57
  else { int rem = idx - 116; row = (1 + (rem >> 1)) * 58 + ((rem & 1) ? 57 : 0); }
  unsigned int* dst = (unsigned int*)(xT + ((size_t)b * PPIX + row) * NCH);
  dst[threadIdx.x] = 0;            // 128 threads * 4B = 256 bf16 = full ci row
}

// ---------------- transpose x [b][ci][pix] fp32 -> xT [b][padpix][ci] bf16 ----------------
__global__ __launch_bounds__(256) void transpose_x(const float* __restrict__ x,
                                                   unsigned short* __restrict__ xT) {
  int pblk = blockIdx.x, ciblk = blockIdx.y, b = blockIdx.z;
  int p0 = pblk * 64, ci0 = ciblk * 64;
  __shared__ unsigned short t[64][65];
  int tj = threadIdx.x & 63, ti = threadIdx.x >> 6;
  const float* xb = x + ((size_t)b * NCH + ci0) * NPIX + p0;
#pragma unroll
  for (int pass = 0; pass < 16; ++pass) {
    int i = pass * 4 + ti;
    t[i][tj] = f2bf(xb[(size_t)i * NPIX + tj]);
  }
  __syncthreads();
  int cio = (threadIdx.x & 31) * 2, jo = threadIdx.x >> 5;
#pragma unroll
  for (int pass = 0; pass < 8; ++pass) {
    int jj = pass * 8 + jo;
    int p = p0 + jj;
    int h = p / 56, w = p % 56;
    int row = (h + 1) * PH + (w + 1);
    unsigned int v = (unsigned int)t[cio][jj] | ((unsigned int)t[cio + 1][jj] << 16);
    *(unsigned int*)(xT + ((size_t)b * PPIX + row) * NCH + ci0 + cio) = v;
  }
}

// ---------------- pool: per-(b,chunk) partial column sums of xT (padding rows are zero) ----------------
__global__ __launch_bounds__(256) void pool_xt(const unsigned short* __restrict__ xT,
                                               float* __restrict__ pp) {
  int chunk = blockIdx.x, b = blockIdx.y;        // 8 x 32
  int r0 = chunk * 421;
  int r1 = r0 + 421; if (r1 > PPIX) r1 = PPIX;
  int cg = threadIdx.x & 63, ro = threadIdx.x >> 6;
  const unsigned short* base = xT + (size_t)b * PPIX * NCH;
  float s0 = 0, s1 = 0, s2 = 0, s3 = 0;
  for (int r = r0 + ro; r < r1; r += 4) {
    uint2 v = *(const uint2*)(base + (size_t)r * NCH + cg * 4);
    s0 += bf2f(v.x & 0xffffu); s1 += bf2f(v.x >> 16);
    s2 += bf2f(v.y & 0xffffu); s3 += bf2f(v.y >> 16);
  }
  __shared__ float red[4][256];
  *(float4*)&red[ro][cg * 4] = make_float4(s0, s1, s2, s3);
  __syncthreads();
  int ci = threadIdx.x;
  float tot = red[0][ci] + red[1][ci] + red[2][ci] + red[3][ci];
  pp[((size_t)b * 8 + chunk) * 256 + ci] = tot;
}

// ---------------- weight tiles: conv_w fp32 [co][ci][3][3] -> wt bf16 [ct][tap][cs][128co][32ci] ----------------
__global__ __launch_bounds__(256) void wtile_k(const float* __restrict__ cw,
                                               unsigned short* __restrict__ wt) {
  int blk = blockIdx.x;                 // 144 = (ct*9+tap)*8 + cs
  int cs = blk & 7; int tc = blk >> 3;
  int tap = tc % 9; int ct = tc / 9;
  unsigned short* dst = wt + (size_t)blk * 4096;
#pragma unroll
  for (int e = 0; e < 16; ++e) {
    int j = e * 256 + threadIdx.x;      // 0..4095
    int ci_l = j & 31, co_l = j >> 5;
    int co = ct * 128 + co_l, ci = cs * 32 + ci_l;
    dst[j] = f2bf(cw[((size_t)co * 256 + ci) * 9 + tap]);
  }
}

// ---------------- head: rmsnorm + phi + sigmoids + sinkhorn -> 3 scalars per batch ----------------
__global__ __launch_bounds__(256) void head_k(const float* __restrict__ pp,
    const float* __restrict__ phi_w, const float* __restrict__ phi_b,
    const float* __restrict__ rms_w, const float* __restrict__ a_pre,
    const float* __restrict__ a_post, const float* __restrict__ a_res,
    float* __restrict__ scales) {
  int b = blockIdx.x;
  int t = threadIdx.x;
  __shared__ float red[4];
  __shared__ float coeff[24];
  float s = 0;
#pragma unroll
  for (int ch = 0; ch < 8; ++ch) s += pp[((size_t)b * 8 + ch) * 256 + t];
  float pooled = s * (1.0f / (float)NPIX);
  // mean square over C (replicated streams -> same as over nC)
  float v = pooled * pooled;
#pragma unroll
  for (int off = 32; off; off >>= 1) v += __shfl_down(v, off);
  if ((t & 63) == 0) red[t >> 6] = v;
  __syncthreads();
  float ms = (red[0] + red[1] + red[2] + red[3]) * (1.0f / 256.0f);
  float inv = rsqrtf(ms + 1e-20f);
  __syncthreads();
  for (int o = 0; o < 24; ++o) {
    float ws_ = 0;
#pragma unroll
    for (int i = 0; i < 4; ++i) ws_ += phi_w[(size_t)o * 1024 + i * 256 + t] * rms_w[i * 256 + t];
    float c = pooled * ws_;
#pragma unroll
    for (int off = 32; off; off >>= 1) c += __shfl_down(c, off);
    if ((t & 63) == 0) red[t >> 6] = c;
    __syncthreads();
    if (t == 0) coeff[o] = inv * (red[0] + red[1] + red[2] + red[3]) + phi_b[o];
    __syncthreads();
  }
  if (t == 0) {
    float ap = a_pre[0], apo = a_post[0], ar = a_res[0];
    float spre = 0, psum = 0;
#pragma unroll
    for (int i = 0; i < 4; ++i) {
      spre += 1.0f / (1.0f + expf(-ap * coeff[i]));
      psum += 2.0f / (1.0f + expf(-apo * coeff[4 + i]));
    }
    float M[4][4];
#pragma unroll
    for (int i = 0; i < 4; ++i)
#pragma unroll
      for (int j = 0; j < 4; ++j) M[i][j] = expf(ar * coeff[8 + i * 4 + j]);
    for (int it = 0; it < 20; ++it) {
#pragma unroll
      for (int i = 0; i < 4; ++i) {
        float rs = M[i][0] + M[i][1] + M[i][2] + M[i][3];
        float rr = 1.0f / rs;
        M[i][0] *= rr; M[i][1] *= rr; M[i][2] *= rr; M[i][3] *= rr;
      }
#pragma unroll
      for (int j = 0; j < 4; ++j) {
        float cs2 = M[0][j] + M[1][j] + M[2][j] + M[3][j];
        float rr = 1.0f / cs2;
        M[0][j] *= rr; M[1][j] *= rr; M[2][j] *= rr; M[3][j] *= rr;
      }
    }
    float r = 0.25f * (M[0][0] + M[1][1] + M[2][2] + M[3][3]);
    float pm = 0.25f * psum;
    scales[b * 4 + 0] = r;          // on x
    scales[b * 4 + 1] = pm * spre;  // on conv(x)
    scales[b * 4 + 2] = pm;         // on conv_b
  }
}

// ---------------- conv as implicit GEMM (m97 structure: 128x128 tile, BK=32, 4 waves) ----------------
__global__ __launch_bounds__(256, 3) void conv_k(
    const unsigned short* __restrict__ xT, const unsigned short* __restrict__ wt,
    const float* __restrict__ x, const float* __restrict__ conv_b,
    const float* __restrict__ scales, float* __restrict__ out) {
  __shared__ __align__(16) unsigned short As[128 * 32];   // [co_l][ci_l]
  __shared__ __align__(16) unsigned short Bs[128 * 32];   // [p_l][ci_l]
  const int ptile = blockIdx.x;   // 25
  const int ct = blockIdx.y;      // 2
  const int b = blockIdx.z;       // 32
  const int p0 = ptile * 128;
  const int tid = threadIdx.x;
  const int wv = tid >> 6, l = tid & 63;
  const int lq = l & 3, lr = l >> 2;

  const float sX = scales[b * 4 + 0], sY = scales[b * 4 + 1], sB = scales[b * 4 + 2];

  // per-thread B-staging rows (fixed for whole K-loop); clamp out-of-range p (masked at store)
  int pa = p0 + wv * 16 + lr;
  int pb = pa + 64;
  if (pa > NPIX - 1) pa = NPIX - 1;
  if (pb > NPIX - 1) pb = NPIX - 1;
  const int r0 = (pa / 56 + 1) * PH + (pa % 56 + 1);
  const int r1 = (pb / 56 + 1) * PH + (pb % 56 + 1);
  const unsigned short* xTb = xT + (size_t)b * PPIX * NCH;

  unsigned short* AsW0 = &As[(wv * 16) * 32];
  unsigned short* AsW1 = &As[(64 + wv * 16) * 32];
  unsigned short* BsW0 = &Bs[(wv * 16) * 32];
  unsigned short* BsW1 = &Bs[(64 + wv * 16) * 32];

  const unsigned short* asrc = wt + (size_t)ct * (9 * 8 * 4096) + wv * 16 * 32 + l * 8;

  f32x4 acc[4][4];
#pragma unroll
  for (int m = 0; m < 4; ++m)
#pragma unroll
    for (int n = 0; n < 4; ++n) acc[m][n] = (f32x4){0.f, 0.f, 0.f, 0.f};

  const int wm = wv >> 1, wn = wv & 1;
  int aoff[4], boff[4];
#pragma unroll
  for (int m = 0; m < 4; ++m) aoff[m] = (wm * 64 + m * 16 + (l & 15)) * 32 + (l >> 4) * 8;
#pragma unroll
  for (int n = 0; n < 4; ++n) boff[n] = (wn * 64 + n * 16 + (l & 15)) * 32 + (l >> 4) * 8;

  for (int kh = 0; kh < 3; ++kh)
    for (int kw = 0; kw < 3; ++kw) {
      const int offt = (kh - 1) * PH + (kw - 1);
      const unsigned short* bs0 = xTb + (size_t)(r0 + offt) * NCH + lq * 8;
      const unsigned short* bs1 = xTb + (size_t)(r1 + offt) * NCH + lq * 8;
#pragma unroll
      for (int cs = 0; cs < 8; ++cs) {
        gload_lds16(asrc, AsW0);
        gload_lds16(asrc + 2048, AsW1);
        gload_lds16(bs0 + cs * 32, BsW0);
        gload_lds16(bs1 + cs * 32, BsW1);
        asrc += 4096;
        __syncthreads();
        bf16x8 af[4], bfr[4];
#pragma unroll
        for (int m = 0; m < 4; ++m) af[m] = *(const bf16x8*)&As[aoff[m]];
#pragma unroll
        for (int n = 0; n < 4; ++n) bfr[n] = *(const bf16x8*)&Bs[boff[n]];
#pragma unroll
        for (int m = 0; m < 4; ++m)
#pragma unroll
          for (int n = 0; n < 4; ++n)
            acc[m][n] = __builtin_amdgcn_mfma_f32_16x16x32_bf16(af[m], bfr[n], acc[m][n], 0, 0, 0);
        __syncthreads();
      }
    }

  // epilogue: out = sX*x + sY*conv + sB*conv_b
  const int lo = l >> 4, lc = l & 15;
#pragma unroll
  for (int m = 0; m < 4; ++m) {
#pragma unroll
    for (int j = 0; j < 4; ++j) {
      int co = ct * 128 + wm * 64 + m * 16 + lo * 4 + j;
      float cbv = sB * conv_b[co];
      size_t rowb = ((size_t)b * NCH + co) * NPIX;
#pragma unroll
      for (int n = 0; n < 4; ++n) {
        int p = p0 + wn * 64 + n * 16 + lc;
        if (p < NPIX) {
          size_t idx = rowb + p;
          out[idx] = sX * x[idx] + sY * acc[m][n][j] + cbv;
        }
      }
    }
  }
}

extern "C" void kernel_launch(void* const* d_in, const int* in_sizes, int n_in,
                              void* d_out, int out_size, void* d_ws, size_t ws_size,
                              hipStream_t stream) {
  const float* x      = (const float*)d_in[0];
  const float* phi_w  = (const float*)d_in[1];
  const float* phi_b  = (const float*)d_in[2];
  const float* rms_w  = (const float*)d_in[3];
  const float* a_pre  = (const float*)d_in[4];
  const float* a_post = (const float*)d_in[5];
  const float* a_res  = (const float*)d_in[6];
  const float* conv_w = (const float*)d_in[7];
  const float* conv_b = (const float*)d_in[8];
  float* out = (float*)d_out;

  char* ws = (char*)d_ws;
  unsigned short* xT = (unsigned short*)ws;
  const size_t XT_BYTES = (size_t)NB * PPIX * NCH * 2;          // 55,115,776
  float* pp = (float*)(ws + XT_BYTES);
  const size_t PP_BYTES = (size_t)NB * 8 * 256 * 4;             // 262,144
  float* scales = (float*)(ws + XT_BYTES + PP_BYTES);
  unsigned short* wt = (unsigned short*)(ws + XT_BYTES + PP_BYTES + 512);

  zero_border<<<dim3(228, NB), dim3(128), 0, stream>>>(xT);
  transpose_x<<<dim3(49, 4, NB), dim3(256), 0, stream>>>(x, xT);
  pool_xt<<<dim3(8, NB), dim3(256), 0, stream>>>(xT, pp);
  wtile_k<<<dim3(144), dim3(256), 0, stream>>>(conv_w, wt);
  head_k<<<dim3(NB), dim3(256), 0, stream>>>(pp, phi_w, phi_b, rms_w, a_pre, a_post, a_res, scales);
  conv_k<<<dim3(25, 2, NB), dim3(256), 0, stream>>>(xT, wt, x, conv_b, scales, out);
}

// Round 2
// 259.105 us; speedup vs baseline: 1.1590x; 1.1590x over previous
//
#include <hip/hip_runtime.h>
#include <stdint.h>

// Problem constants
#define NB   32
#define NCH  256
#define NPIX 3136      // 56*56
#define PH   58        // padded width/height (56+2)
#define PPIX 3364      // 58*58

typedef __bf16 bf16x8 __attribute__((ext_vector_type(8)));
typedef float  f32x4  __attribute__((ext_vector_type(4)));

__device__ __forceinline__ unsigned short f2bf(float f) {
  unsigned int u = __float_as_uint(f);
  u += 0x7fff + ((u >> 16) & 1);           // RNE
  return (unsigned short)(u >> 16);
}
__device__ __forceinline__ float bf2f(unsigned int us) {
  return __uint_as_float(us << 16);
}

// async global->LDS, 16B per lane. LDS ptr must be wave-uniform; HW adds lane*16.
__device__ __forceinline__ void gload_lds16(const void* g, void* l) {
  __builtin_amdgcn_global_load_lds(
      (const __attribute__((address_space(1))) unsigned int*)(uintptr_t)g,
      (__attribute__((address_space(3))) unsigned int*)(unsigned int)(uintptr_t)l,
      16, 0, 0);
}

// ---------------- prep: weight tiles + zero xT borders (fused, independent work) ----------------
// wt layout: [cs 8][tap 9][co 256][ci_l 32] bf16  (stage = cs*9+tap, 16 KB each)
__global__ __launch_bounds__(256) void prep_k(const float* __restrict__ cw,
                                              unsigned short* __restrict__ wt,
                                              unsigned short* __restrict__ xT) {
  int blk = blockIdx.x;
  int tid = threadIdx.x;
  if (blk < 144) {
    int stage = blk >> 1, half = blk & 1;
    int tap = stage % 9, cs = stage / 9;
    unsigned short* dst = wt + (size_t)stage * 8192 + half * 4096;
#pragma unroll
    for (int e = 0; e < 16; ++e) {
      int j = e * 256 + tid;            // 0..4095 over [128co][32ci]
      int ci_l = j & 31, co_l = j >> 5;
      int co = half * 128 + co_l, ci = cs * 32 + ci_l;
      dst[j] = f2bf(cw[((size_t)co * 256 + ci) * 9 + tap]);
    }
  } else {
    int g = (blk - 144) * 256 + tid;    // uint index, < 933888
    int b = g / 29184;                   // 228 border rows * 128 uints
    int rem = g - b * 29184;
    int ridx = rem >> 7, ui = rem & 127;
    int row;
    if (ridx < 58)       row = ridx;
    else if (ridx < 116) row = 57 * 58 + (ridx - 58);
    else { int r2 = ridx - 116; row = (1 + (r2 >> 1)) * 58 + ((r2 & 1) ? 57 : 0); }
    ((unsigned int*)(xT + ((size_t)b * PPIX + row) * NCH))[ui] = 0;
  }
}

// ---------------- transpose x [b][ci][pix] fp32 -> xT [b][padpix][ci] bf16, + partial pooling ----------------
__global__ __launch_bounds__(256) void transpose_x(const float* __restrict__ x,
                                                   unsigned short* __restrict__ xT,
                                                   float* __restrict__ pp2) {
  int pblk = blockIdx.x, ciblk = blockIdx.y, b = blockIdx.z;
  int p0 = pblk * 64, ci0 = ciblk * 64;
  __shared__ unsigned short t[64][65];
  int tid = threadIdx.x;
  int pq = tid & 15, cq = tid >> 4;
  const float* xb = x + ((size_t)b * NCH + ci0) * NPIX + p0;
#pragma unroll
  for (int pass = 0; pass < 4; ++pass) {
    int ci_l = pass * 16 + cq;
    float4 v = *(const float4*)&xb[(size_t)ci_l * NPIX + pq * 4];
    t[ci_l][pq * 4 + 0] = f2bf(v.x);
    t[ci_l][pq * 4 + 1] = f2bf(v.y);
    t[ci_l][pq * 4 + 2] = f2bf(v.z);
    t[ci_l][pq * 4 + 3] = f2bf(v.w);
  }
  __syncthreads();
  // partial pooling: column sums over this block's 64 pixels for its 64 ci
  if (tid < 64) {
    float s = 0;
#pragma unroll
    for (int p = 0; p < 64; ++p) s += bf2f(t[tid][p]);
    pp2[((size_t)b * 49 + pblk) * 256 + ci0 + tid] = s;
  }
  // write transposed, bf16-paired
  int cio = (tid & 31) * 2, jo = tid >> 5;
#pragma unroll
  for (int pass = 0; pass < 8; ++pass) {
    int jj = pass * 8 + jo;
    int p = p0 + jj;
    int h = p / 56, w = p % 56;
    int row = (h + 1) * PH + (w + 1);
    unsigned int v = (unsigned int)t[cio][jj] | ((unsigned int)t[cio + 1][jj] << 16);
    *(unsigned int*)(xT + ((size_t)b * PPIX + row) * NCH + ci0 + cio) = v;
  }
}

// ---------------- head: rmsnorm + phi + sigmoids + sinkhorn -> 3 scalars per batch ----------------
__global__ __launch_bounds__(256) void head_k(const float* __restrict__ pp2,
    const float* __restrict__ phi_w, const float* __restrict__ phi_b,
    const float* __restrict__ rms_w, const float* __restrict__ a_pre,
    const float* __restrict__ a_post, const float* __restrict__ a_res,
    float* __restrict__ scales) {
  int b = blockIdx.x;
  int t = threadIdx.x;
  __shared__ float red[4];
  __shared__ float coeff[24];
  float s = 0;
  for (int ch = 0; ch < 49; ++ch) s += pp2[((size_t)b * 49 + ch) * 256 + t];
  float pooled = s * (1.0f / (float)NPIX);
  float v = pooled * pooled;
#pragma unroll
  for (int off = 32; off; off >>= 1) v += __shfl_down(v, off);
  if ((t & 63) == 0) red[t >> 6] = v;
  __syncthreads();
  float ms = (red[0] + red[1] + red[2] + red[3]) * (1.0f / 256.0f);
  float inv = rsqrtf(ms + 1e-20f);
  __syncthreads();
  for (int o = 0; o < 24; ++o) {
    float ws_ = 0;
#pragma unroll
    for (int i = 0; i < 4; ++i) ws_ += phi_w[(size_t)o * 1024 + i * 256 + t] * rms_w[i * 256 + t];
    float c = pooled * ws_;
#pragma unroll
    for (int off = 32; off; off >>= 1) c += __shfl_down(c, off);
    if ((t & 63) == 0) red[t >> 6] = c;
    __syncthreads();
    if (t == 0) coeff[o] = inv * (red[0] + red[1] + red[2] + red[3]) + phi_b[o];
    __syncthreads();
  }
  if (t == 0) {
    float ap = a_pre[0], apo = a_post[0], ar = a_res[0];
    float spre = 0, psum = 0;
#pragma unroll
    for (int i = 0; i < 4; ++i) {
      spre += 1.0f / (1.0f + expf(-ap * coeff[i]));
      psum += 2.0f / (1.0f + expf(-apo * coeff[4 + i]));
    }
    float M[4][4];
#pragma unroll
    for (int i = 0; i < 4; ++i)
#pragma unroll
      for (int j = 0; j < 4; ++j) M[i][j] = expf(ar * coeff[8 + i * 4 + j]);
    for (int it = 0; it < 20; ++it) {
#pragma unroll
      for (int i = 0; i < 4; ++i) {
        float rs = M[i][0] + M[i][1] + M[i][2] + M[i][3];
        float rr = 1.0f / rs;
        M[i][0] *= rr; M[i][1] *= rr; M[i][2] *= rr; M[i][3] *= rr;
      }
#pragma unroll
      for (int j = 0; j < 4; ++j) {
        float cs2 = M[0][j] + M[1][j] + M[2][j] + M[3][j];
        float rr = 1.0f / cs2;
        M[0][j] *= rr; M[1][j] *= rr; M[2][j] *= rr; M[3][j] *= rr;
      }
    }
    float r = 0.25f * (M[0][0] + M[1][1] + M[2][2] + M[3][3]);
    float pm = 0.25f * psum;
    scales[b * 4 + 0] = r;          // on x
    scales[b * 4 + 1] = pm * spre;  // on conv(x)
    scales[b * 4 + 2] = pm;         // on conv_b
  }
}

// ---------------- conv as implicit GEMM: 256co x 128pix tile, BK=32, cs-outer/tap-inner, dbuf prefetch ----------------
__global__ __launch_bounds__(256, 2) void conv_k(
    const unsigned short* __restrict__ xT, const unsigned short* __restrict__ wt,
    const float* __restrict__ x, const float* __restrict__ conv_b,
    const float* __restrict__ scales, float* __restrict__ out) {
  __shared__ __align__(16) unsigned short As[2][256 * 32];   // 16 KB each: [co][ci_l]
  __shared__ __align__(16) unsigned short Bs[2][128 * 32];   // 8 KB each:  [p_l][ci_l]
  const int ptile = blockIdx.x;   // 25
  const int b = blockIdx.y;       // 32
  const int p0 = ptile * 128;
  const int tid = threadIdx.x;
  const int wv = tid >> 6, l = tid & 63;
  const int lq = l & 3, lr = l >> 2;

  const float sX = scales[b * 4 + 0], sY = scales[b * 4 + 1], sB = scales[b * 4 + 2];

  // B staging rows (fixed all K); clamp OOB pixels (masked at store)
  int pa = p0 + wv * 16 + lr; if (pa > NPIX - 1) pa = NPIX - 1;
  int pb = pa + 64;           if (pb > NPIX - 1) pb = NPIX - 1;
  const int r0 = (pa / 56 + 1) * PH + (pa % 56 + 1);
  const int r1 = (pb / 56 + 1) * PH + (pb % 56 + 1);
  const char* xTb = (const char*)xT + (size_t)b * PPIX * NCH * 2;
  const char* bsrc0 = xTb + (size_t)r0 * 512 + lq * 16;
  const char* bsrc1 = xTb + (size_t)r1 * 512 + lq * 16;
  const char* asrc  = (const char*)wt + wv * 1024 + l * 16;

  char* adst0 = (char*)&As[0][0] + wv * 1024;
  char* adst1 = (char*)&As[1][0] + wv * 1024;
  char* bdst0 = (char*)&Bs[0][0] + wv * 1024;
  char* bdst1 = (char*)&Bs[1][0] + wv * 1024;

#define STAGE(AD, BD, ASRC, BOFF) do {                 \
    gload_lds16((ASRC),         (AD));                 \
    gload_lds16((ASRC) + 4096,  (AD) + 4096);          \
    gload_lds16((ASRC) + 8192,  (AD) + 8192);          \
    gload_lds16((ASRC) + 12288, (AD) + 12288);         \
    gload_lds16(bsrc0 + (BOFF), (BD));                 \
    gload_lds16(bsrc1 + (BOFF), (BD) + 4096);          \
  } while (0)

  // tap order (kh*3+kw) -> padded-row byte shift
  const int tapoff[9] = {-59 * 512, -58 * 512, -57 * 512, -512, 0, 512, 57 * 512, 58 * 512, 59 * 512};

  f32x4 acc[8][4];
#pragma unroll
  for (int m = 0; m < 8; ++m)
#pragma unroll
    for (int n = 0; n < 4; ++n) acc[m][n] = (f32x4){0.f, 0.f, 0.f, 0.f};

  const int wm = wv >> 1, wn = wv & 1;
  int aoff[8], boff[4];
#pragma unroll
  for (int m = 0; m < 8; ++m) aoff[m] = (wm * 128 + m * 16 + (l & 15)) * 32 + (l >> 4) * 8;
#pragma unroll
  for (int n = 0; n < 4; ++n) boff[n] = (wn * 64 + n * 16 + (l & 15)) * 32 + (l >> 4) * 8;

  // prologue: stage (cs=0, tap=0) into buf 0
  STAGE(adst0, bdst0, asrc, tapoff[0]);
  asrc += 16384;
  __syncthreads();

  int cur = 0;
  for (int s = 0; s < 72; ++s) {
    if (s < 71) {
      int ns = s + 1;
      int ncs = ns / 9;
      int ntap = ns - ncs * 9;
      char* ad = cur ? adst0 : adst1;
      char* bd = cur ? bdst0 : bdst1;
      STAGE(ad, bd, asrc, tapoff[ntap] + ncs * 64);
      asrc += 16384;
    }
    const unsigned short* Ab = cur ? &As[1][0] : &As[0][0];
    const unsigned short* Bb = cur ? &Bs[1][0] : &Bs[0][0];
    bf16x8 af[8], bfr[4];
#pragma unroll
    for (int m = 0; m < 8; ++m) af[m] = *(const bf16x8*)&Ab[aoff[m]];
#pragma unroll
    for (int n = 0; n < 4; ++n) bfr[n] = *(const bf16x8*)&Bb[boff[n]];
#pragma unroll
    for (int m = 0; m < 8; ++m)
#pragma unroll
      for (int n = 0; n < 4; ++n)
        acc[m][n] = __builtin_amdgcn_mfma_f32_16x16x32_bf16(af[m], bfr[n], acc[m][n], 0, 0, 0);
    __syncthreads();
    cur ^= 1;
  }
#undef STAGE

  // epilogue: out = sX*x + sY*conv + sB*conv_b
  const int lo = l >> 4, lc = l & 15;
#pragma unroll
  for (int m = 0; m < 8; ++m) {
#pragma unroll
    for (int j = 0; j < 4; ++j) {
      int co = wm * 128 + m * 16 + lo * 4 + j;
      float cbv = sB * conv_b[co];
      size_t rowb = ((size_t)b * NCH + co) * NPIX;
#pragma unroll
      for (int n = 0; n < 4; ++n) {
        int p = p0 + wn * 64 + n * 16 + lc;
        if (p < NPIX) {
          size_t idx = rowb + p;
          out[idx] = sX * x[idx] + sY * acc[m][n][j] + cbv;
        }
      }
    }
  }
}

extern "C" void kernel_launch(void* const* d_in, const int* in_sizes, int n_in,
                              void* d_out, int out_size, void* d_ws, size_t ws_size,
                              hipStream_t stream) {
  const float* x      = (const float*)d_in[0];
  const float* phi_w  = (const float*)d_in[1];
  const float* phi_b  = (const float*)d_in[2];
  const float* rms_w  = (const float*)d_in[3];
  const float* a_pre  = (const float*)d_in[4];
  const float* a_post = (const float*)d_in[5];
  const float* a_res  = (const float*)d_in[6];
  const float* conv_w = (const float*)d_in[7];
  const float* conv_b = (const float*)d_in[8];
  float* out = (float*)d_out;

  char* ws = (char*)d_ws;
  unsigned short* xT = (unsigned short*)ws;
  const size_t XT_BYTES = (size_t)NB * PPIX * NCH * 2;            // 55,115,776
  float* pp2 = (float*)(ws + XT_BYTES);
  const size_t PP_BYTES = (size_t)NB * 49 * 256 * 4;              // 1,605,632
  float* scales = (float*)(ws + XT_BYTES + PP_BYTES);
  unsigned short* wt = (unsigned short*)(ws + XT_BYTES + PP_BYTES + 512);

  prep_k<<<dim3(144 + 3648), dim3(256), 0, stream>>>(conv_w, wt, xT);
  transpose_x<<<dim3(49, 4, NB), dim3(256), 0, stream>>>(x, xT, pp2);
  head_k<<<dim3(NB), dim3(256), 0, stream>>>(pp2, phi_w, phi_b, rms_w, a_pre, a_post, a_res, scales);
  conv_k<<<dim3(25, NB), dim3(256), 0, stream>>>(xT, wt, x, conv_b, scales, out);
}

// Round 3
// 245.763 us; speedup vs baseline: 1.2219x; 1.0543x over previous
//
#include <hip/hip_runtime.h>
#include <stdint.h>

// Problem constants
#define NB   32
#define NCH  256
#define NPIX 3136      // 56*56
#define PH   58        // padded width/height (56+2)
#define PPIX 3364      // 58*58

typedef __bf16 bf16x8 __attribute__((ext_vector_type(8)));
typedef float  f32x4  __attribute__((ext_vector_type(4)));

__device__ __forceinline__ unsigned short f2bf(float f) {
  unsigned int u = __float_as_uint(f);
  u += 0x7fff + ((u >> 16) & 1);           // RNE
  return (unsigned short)(u >> 16);
}
__device__ __forceinline__ float bf2f(unsigned int us) {
  return __uint_as_float(us << 16);
}

// async global->LDS, 16B per lane. LDS ptr must be wave-uniform; HW adds lane*16.
__device__ __forceinline__ void gload_lds16(const void* g, void* l) {
  __builtin_amdgcn_global_load_lds(
      (const __attribute__((address_space(1))) unsigned int*)(uintptr_t)g,
      (__attribute__((address_space(3))) unsigned int*)(unsigned int)(uintptr_t)l,
      16, 0, 0);
}

// ---------------- prep: weight tiles + zero xT borders (fused, independent work) ----------------
// wt layout: [stage=cs*9+tap][co 256][slot 4][e 8] bf16, with bank-swizzle baked in:
// LDS slot s holds global ci-slot (s ^ ((co>>1)&3)), so linear global_load_lds staging
// yields the swizzled LDS layout read by conv_k.
__global__ __launch_bounds__(256) void prep_k(const float* __restrict__ cw,
                                              unsigned short* __restrict__ wt,
                                              unsigned short* __restrict__ xT) {
  int blk = blockIdx.x;
  int tid = threadIdx.x;
  if (blk < 144) {
    int stage = blk >> 1, half = blk & 1;
    int tap = stage % 9, cs = stage / 9;
    unsigned short* dst = wt + (size_t)stage * 8192 + half * 4096;
#pragma unroll
    for (int e8 = 0; e8 < 16; ++e8) {
      int j = e8 * 256 + tid;           // 0..4095 over [128co][32ci]
      int ci_l = j & 31, co_l = j >> 5;
      int slot = ci_l >> 3, e = ci_l & 7;
      int slot_g = slot ^ ((co_l >> 1) & 3);        // inverse swizzle at source
      int co = half * 128 + co_l, ci = cs * 32 + slot_g * 8 + e;
      dst[j] = f2bf(cw[((size_t)co * 256 + ci) * 9 + tap]);
    }
  } else {
    int g = (blk - 144) * 256 + tid;    // uint index, < 933888
    int b = g / 29184;                   // 228 border rows * 128 uints
    int rem = g - b * 29184;
    int ridx = rem >> 7, ui = rem & 127;
    int row;
    if (ridx < 58)       row = ridx;
    else if (ridx < 116) row = 57 * 58 + (ridx - 58);
    else { int r2 = ridx - 116; row = (1 + (r2 >> 1)) * 58 + ((r2 & 1) ? 57 : 0); }
    ((unsigned int*)(xT + ((size_t)b * PPIX + row) * NCH))[ui] = 0;
  }
}

// ---------------- transpose x [b][ci][pix] fp32 -> xT [b][padpix][ci] bf16, + partial pooling ----------------
__global__ __launch_bounds__(256) void transpose_x(const float* __restrict__ x,
                                                   unsigned short* __restrict__ xT,
                                                   float* __restrict__ pp2) {
  int pblk = blockIdx.x, ciblk = blockIdx.y, b = blockIdx.z;
  int p0 = pblk * 64, ci0 = ciblk * 64;
  __shared__ unsigned short t[64][65];
  int tid = threadIdx.x;
  int pq = tid & 15, cq = tid >> 4;
  const float* xb = x + ((size_t)b * NCH + ci0) * NPIX + p0;
#pragma unroll
  for (int pass = 0; pass < 4; ++pass) {
    int ci_l = pass * 16 + cq;
    float4 v = *(const float4*)&xb[(size_t)ci_l * NPIX + pq * 4];
    t[ci_l][pq * 4 + 0] = f2bf(v.x);
    t[ci_l][pq * 4 + 1] = f2bf(v.y);
    t[ci_l][pq * 4 + 2] = f2bf(v.z);
    t[ci_l][pq * 4 + 3] = f2bf(v.w);
  }
  __syncthreads();
  // partial pooling: column sums over this block's 64 pixels for its 64 ci
  if (tid < 64) {
    float s = 0;
#pragma unroll
    for (int p = 0; p < 64; ++p) s += bf2f(t[tid][p]);
    pp2[((size_t)b * 49 + pblk) * 256 + ci0 + tid] = s;
  }
  // write transposed, bf16-paired
  int cio = (tid & 31) * 2, jo = tid >> 5;
#pragma unroll
  for (int pass = 0; pass < 8; ++pass) {
    int jj = pass * 8 + jo;
    int p = p0 + jj;
    int h = p / 56, w = p % 56;
    int row = (h + 1) * PH + (w + 1);
    unsigned int v = (unsigned int)t[cio][jj] | ((unsigned int)t[cio + 1][jj] << 16);
    *(unsigned int*)(xT + ((size_t)b * PPIX + row) * NCH + ci0 + cio) = v;
  }
}

// ---------------- head: rmsnorm + phi + sigmoids + sinkhorn -> 3 scalars per batch ----------------
__global__ __launch_bounds__(256) void head_k(const float* __restrict__ pp2,
    const float* __restrict__ phi_w, const float* __restrict__ phi_b,
    const float* __restrict__ rms_w, const float* __restrict__ a_pre,
    const float* __restrict__ a_post, const float* __restrict__ a_res,
    float* __restrict__ scales) {
  int b = blockIdx.x;
  int t = threadIdx.x;
  __shared__ float red[4];
  __shared__ float coeff[24];
  float s = 0;
  for (int ch = 0; ch < 49; ++ch) s += pp2[((size_t)b * 49 + ch) * 256 + t];
  float pooled = s * (1.0f / (float)NPIX);
  float v = pooled * pooled;
#pragma unroll
  for (int off = 32; off; off >>= 1) v += __shfl_down(v, off);
  if ((t & 63) == 0) red[t >> 6] = v;
  __syncthreads();
  float ms = (red[0] + red[1] + red[2] + red[3]) * (1.0f / 256.0f);
  float inv = rsqrtf(ms + 1e-20f);
  __syncthreads();
  for (int o = 0; o < 24; ++o) {
    float ws_ = 0;
#pragma unroll
    for (int i = 0; i < 4; ++i) ws_ += phi_w[(size_t)o * 1024 + i * 256 + t] * rms_w[i * 256 + t];
    float c = pooled * ws_;
#pragma unroll
    for (int off = 32; off; off >>= 1) c += __shfl_down(c, off);
    if ((t & 63) == 0) red[t >> 6] = c;
    __syncthreads();
    if (t == 0) coeff[o] = inv * (red[0] + red[1] + red[2] + red[3]) + phi_b[o];
    __syncthreads();
  }
  if (t == 0) {
    float ap = a_pre[0], apo = a_post[0], ar = a_res[0];
    float spre = 0, psum = 0;
#pragma unroll
    for (int i = 0; i < 4; ++i) {
      spre += 1.0f / (1.0f + expf(-ap * coeff[i]));
      psum += 2.0f / (1.0f + expf(-apo * coeff[4 + i]));
    }
    float M[4][4];
#pragma unroll
    for (int i = 0; i < 4; ++i)
#pragma unroll
      for (int j = 0; j < 4; ++j) M[i][j] = expf(ar * coeff[8 + i * 4 + j]);
    for (int it = 0; it < 20; ++it) {
#pragma unroll
      for (int i = 0; i < 4; ++i) {
        float rs = M[i][0] + M[i][1] + M[i][2] + M[i][3];
        float rr = 1.0f / rs;
        M[i][0] *= rr; M[i][1] *= rr; M[i][2] *= rr; M[i][3] *= rr;
      }
#pragma unroll
      for (int j = 0; j < 4; ++j) {
        float cs2 = M[0][j] + M[1][j] + M[2][j] + M[3][j];
        float rr = 1.0f / cs2;
        M[0][j] *= rr; M[1][j] *= rr; M[2][j] *= rr; M[3][j] *= rr;
      }
    }
    float r = 0.25f * (M[0][0] + M[1][1] + M[2][2] + M[3][3]);
    float pm = 0.25f * psum;
    scales[b * 4 + 0] = r;          // on x
    scales[b * 4 + 1] = pm * spre;  // on conv(x)
    scales[b * 4 + 2] = pm;         // on conv_b
  }
}

// ---------------- conv implicit GEMM: 256co x 128pix, BK=32, triple-buffer LDS,
// counted vmcnt (never 0 in steady state), one raw s_barrier/stage, XOR bank swizzle ----------------
__global__ __launch_bounds__(256, 2) void conv_k(
    const unsigned short* __restrict__ xT, const unsigned short* __restrict__ wt,
    const float* __restrict__ x, const float* __restrict__ conv_b,
    const float* __restrict__ scales, float* __restrict__ out) {
  __shared__ __align__(16) char lds[3][24576];   // per buf: A 16 KB [co][32ci] + B 8 KB [pix][32ci]
  const int ptile = blockIdx.x;   // 25
  const int b = blockIdx.y;       // 32
  const int p0 = ptile * 128;
  const int tid = threadIdx.x;
  const int wv = tid >> 6, l = tid & 63;
  const int lq = l & 3, lr = l >> 2;
  const int lqs = lq ^ ((l >> 3) & 3);          // source-side swizzle for B staging

  const float sX = scales[b * 4 + 0], sY = scales[b * 4 + 1], sB = scales[b * 4 + 2];

  // B staging rows (fixed all K); clamp OOB pixels (masked at store)
  int pa = p0 + wv * 16 + lr; if (pa > NPIX - 1) pa = NPIX - 1;
  int pb = pa + 64;           if (pb > NPIX - 1) pb = NPIX - 1;
  const int r0 = (pa / 56 + 1) * PH + (pa % 56 + 1);
  const int r1 = (pb / 56 + 1) * PH + (pb % 56 + 1);
  const char* xTb = (const char*)xT + (size_t)b * PPIX * NCH * 2;
  const char* bsrc0 = xTb + (size_t)r0 * 512 + lqs * 16;
  const char* bsrc1 = xTb + (size_t)r1 * 512 + lqs * 16;
  const char* asrc  = (const char*)wt + wv * 1024 + l * 16;

#define STAGE(c, boff) do {                                   \
    char* ad_ = &lds[c][0]     + wv * 1024;                   \
    char* bd_ = &lds[c][16384] + wv * 1024;                   \
    gload_lds16(asrc,          ad_);                          \
    gload_lds16(asrc + 4096,   ad_ + 4096);                   \
    gload_lds16(asrc + 8192,   ad_ + 8192);                   \
    gload_lds16(asrc + 12288,  ad_ + 12288);                  \
    gload_lds16(bsrc0 + (boff), bd_);                         \
    gload_lds16(bsrc1 + (boff), bd_ + 4096);                  \
    asrc += 16384;                                            \
  } while (0)

  f32x4 acc[8][4];
#pragma unroll
  for (int m = 0; m < 8; ++m)
#pragma unroll
    for (int n = 0; n < 4; ++n) acc[m][n] = (f32x4){0.f, 0.f, 0.f, 0.f};

  const int wm = wv >> 1, wn = wv & 1;
  int aoff[8], boff[4];      // BYTE offsets, bank-swizzled: slot ^= (row>>1)&3
#pragma unroll
  for (int m = 0; m < 8; ++m) {
    int row = wm * 128 + m * 16 + (l & 15);
    aoff[m] = row * 64 + ((((l >> 4) ^ (row >> 1)) & 3) << 4);
  }
#pragma unroll
  for (int n = 0; n < 4; ++n) {
    int row = wn * 64 + n * 16 + (l & 15);
    boff[n] = row * 64 + ((((l >> 4) ^ (row >> 1)) & 3) << 4);
  }

  // prologue: stages 0 (kh0,kw0) and 1 (kh0,kw1)
  STAGE(0, -59 * 512);
  STAGE(1, -58 * 512);

  int kh2 = 0, kw2 = 2, cs2 = 0;   // descriptor of stage s+2
  int c = 0;
  for (int s = 0; s < 72; ++s) {
    if (s < 70) { asm volatile("s_waitcnt vmcnt(6)" ::: "memory"); }
    else        { asm volatile("s_waitcnt vmcnt(0)" ::: "memory"); }
    __builtin_amdgcn_s_barrier();
    __builtin_amdgcn_sched_barrier(0);
    if (s < 70) {
      int boff2 = ((kh2 - 1) * 58 + (kw2 - 1)) * 512 + cs2 * 64;
      int c2 = c + 2; if (c2 >= 3) c2 -= 3;
      STAGE(c2, boff2);
      if (++kw2 == 3) { kw2 = 0; if (++kh2 == 3) { kh2 = 0; ++cs2; } }
    }
    const char* Ab = &lds[c][0];
    const char* Bb = &lds[c][16384];
    bf16x8 af[8], bfr[4];
#pragma unroll
    for (int m = 0; m < 8; ++m) af[m] = *(const bf16x8*)(Ab + aoff[m]);
#pragma unroll
    for (int n = 0; n < 4; ++n) bfr[n] = *(const bf16x8*)(Bb + boff[n]);
    __builtin_amdgcn_s_setprio(1);
#pragma unroll
    for (int m = 0; m < 8; ++m)
#pragma unroll
      for (int n = 0; n < 4; ++n)
        acc[m][n] = __builtin_amdgcn_mfma_f32_16x16x32_bf16(af[m], bfr[n], acc[m][n], 0, 0, 0);
    __builtin_amdgcn_s_setprio(0);
    if (++c == 3) c = 0;
  }
#undef STAGE

  // epilogue: out = sX*x + sY*conv + sB*conv_b
  const int lo = l >> 4, lc = l & 15;
#pragma unroll
  for (int m = 0; m < 8; ++m) {
#pragma unroll
    for (int j = 0; j < 4; ++j) {
      int co = wm * 128 + m * 16 + lo * 4 + j;
      float cbv = sB * conv_b[co];
      size_t rowb = ((size_t)b * NCH + co) * NPIX;
#pragma unroll
      for (int n = 0; n < 4; ++n) {
        int p = p0 + wn * 64 + n * 16 + lc;
        if (p < NPIX) {
          size_t idx = rowb + p;
          out[idx] = sX * x[idx] + sY * acc[m][n][j] + cbv;
        }
      }
    }
  }
}

extern "C" void kernel_launch(void* const* d_in, const int* in_sizes, int n_in,
                              void* d_out, int out_size, void* d_ws, size_t ws_size,
                              hipStream_t stream) {
  const float* x      = (const float*)d_in[0];
  const float* phi_w  = (const float*)d_in[1];
  const float* phi_b  = (const float*)d_in[2];
  const float* rms_w  = (const float*)d_in[3];
  const float* a_pre  = (const float*)d_in[4];
  const float* a_post = (const float*)d_in[5];
  const float* a_res  = (const float*)d_in[6];
  const float* conv_w = (const float*)d_in[7];
  const float* conv_b = (const float*)d_in[8];
  float* out = (float*)d_out;

  char* ws = (char*)d_ws;
  unsigned short* xT = (unsigned short*)ws;
  const size_t XT_BYTES = (size_t)NB * PPIX * NCH * 2;            // 55,115,776
  float* pp2 = (float*)(ws + XT_BYTES);
  const size_t PP_BYTES = (size_t)NB * 49 * 256 * 4;              // 1,605,632
  float* scales = (float*)(ws + XT_BYTES + PP_BYTES);
  unsigned short* wt = (unsigned short*)(ws + XT_BYTES + PP_BYTES + 512);

  prep_k<<<dim3(144 + 3648), dim3(256), 0, stream>>>(conv_w, wt, xT);
  transpose_x<<<dim3(49, 4, NB), dim3(256), 0, stream>>>(x, xT, pp2);
  head_k<<<dim3(NB), dim3(256), 0, stream>>>(pp2, phi_w, phi_b, rms_w, a_pre, a_post, a_res, scales);
  conv_k<<<dim3(25, NB), dim3(256), 0, stream>>>(xT, wt, x, conv_b, scales, out);
}

// Round 4
// 208.463 us; speedup vs baseline: 1.4405x; 1.1789x over previous
//
#include <hip/hip_runtime.h>
#include <stdint.h>

// Problem constants
#define NB   32
#define NCH  256
#define NPIX 3136      // 56*56
#define PH   58        // padded width/height (56+2)
#define PPIX 3364      // 58*58

typedef __bf16 bf16x8 __attribute__((ext_vector_type(8)));
typedef float  f32x4  __attribute__((ext_vector_type(4)));

__device__ __forceinline__ unsigned short f2bf(float f) {
  unsigned int u = __float_as_uint(f);
  u += 0x7fff + ((u >> 16) & 1);           // RNE
  return (unsigned short)(u >> 16);
}
__device__ __forceinline__ float bf2f(unsigned int us) {
  return __uint_as_float(us << 16);
}

// async global->LDS, 16B per lane. LDS ptr must be wave-uniform; HW adds lane*16.
__device__ __forceinline__ void gload_lds16(const void* g, void* l) {
  __builtin_amdgcn_global_load_lds(
      (const __attribute__((address_space(1))) unsigned int*)(uintptr_t)g,
      (__attribute__((address_space(3))) unsigned int*)(unsigned int)(uintptr_t)l,
      16, 0, 0);
}

// ---------------- prep: weight tiles + zero xT borders (fused, independent work) ----------------
// wt layout: [stage=cs*9+tap][co 256][slot 4][e 8] bf16, bank-swizzle baked in:
// LDS slot s holds global ci-slot (s ^ ((co>>1)&3)).
__global__ __launch_bounds__(256) void prep_k(const float* __restrict__ cw,
                                              unsigned short* __restrict__ wt,
                                              unsigned short* __restrict__ xT) {
  int blk = blockIdx.x;
  int tid = threadIdx.x;
  if (blk < 144) {
    int stage = blk >> 1, half = blk & 1;
    int tap = stage % 9, cs = stage / 9;
    unsigned short* dst = wt + (size_t)stage * 8192 + half * 4096;
#pragma unroll
    for (int e8 = 0; e8 < 16; ++e8) {
      int j = e8 * 256 + tid;           // 0..4095 over [128co][32ci]
      int ci_l = j & 31, co_l = j >> 5;
      int slot = ci_l >> 3, e = ci_l & 7;
      int slot_g = slot ^ ((co_l >> 1) & 3);        // inverse swizzle at source
      int co = half * 128 + co_l, ci = cs * 32 + slot_g * 8 + e;
      dst[j] = f2bf(cw[((size_t)co * 256 + ci) * 9 + tap]);
    }
  } else {
    int g = (blk - 144) * 256 + tid;    // uint index, < 933888
    int b = g / 29184;                   // 228 border rows * 128 uints
    int rem = g - b * 29184;
    int ridx = rem >> 7, ui = rem & 127;
    int row;
    if (ridx < 58)       row = ridx;
    else if (ridx < 116) row = 57 * 58 + (ridx - 58);
    else { int r2 = ridx - 116; row = (1 + (r2 >> 1)) * 58 + ((r2 & 1) ? 57 : 0); }
    ((unsigned int*)(xT + ((size_t)b * PPIX + row) * NCH))[ui] = 0;
  }
}

// ---------------- transpose x [b][ci][pix] fp32 -> xT [b][padpix][ci] bf16, + partial pooling ----------------
__global__ __launch_bounds__(256) void transpose_x(const float* __restrict__ x,
                                                   unsigned short* __restrict__ xT,
                                                   float* __restrict__ pp2) {
  int pblk = blockIdx.x, ciblk = blockIdx.y, b = blockIdx.z;
  int p0 = pblk * 64, ci0 = ciblk * 64;
  __shared__ unsigned short t[64][65];
  int tid = threadIdx.x;
  int pq = tid & 15, cq = tid >> 4;
  const float* xb = x + ((size_t)b * NCH + ci0) * NPIX + p0;
#pragma unroll
  for (int pass = 0; pass < 4; ++pass) {
    int ci_l = pass * 16 + cq;
    float4 v = *(const float4*)&xb[(size_t)ci_l * NPIX + pq * 4];
    t[ci_l][pq * 4 + 0] = f2bf(v.x);
    t[ci_l][pq * 4 + 1] = f2bf(v.y);
    t[ci_l][pq * 4 + 2] = f2bf(v.z);
    t[ci_l][pq * 4 + 3] = f2bf(v.w);
  }
  __syncthreads();
  if (tid < 64) {
    float s = 0;
#pragma unroll
    for (int p = 0; p < 64; ++p) s += bf2f(t[tid][p]);
    pp2[((size_t)b * 49 + pblk) * 256 + ci0 + tid] = s;
  }
  int cio = (tid & 31) * 2, jo = tid >> 5;
#pragma unroll
  for (int pass = 0; pass < 8; ++pass) {
    int jj = pass * 8 + jo;
    int p = p0 + jj;
    int h = p / 56, w = p % 56;
    int row = (h + 1) * PH + (w + 1);
    unsigned int v = (unsigned int)t[cio][jj] | ((unsigned int)t[cio + 1][jj] << 16);
    *(unsigned int*)(xT + ((size_t)b * PPIX + row) * NCH + ci0 + cio) = v;
  }
}

// ---------------- head: rmsnorm + phi + sigmoids + sinkhorn -> 3 scalars per batch ----------------
__global__ __launch_bounds__(256) void head_k(const float* __restrict__ pp2,
    const float* __restrict__ phi_w, const float* __restrict__ phi_b,
    const float* __restrict__ rms_w, const float* __restrict__ a_pre,
    const float* __restrict__ a_post, const float* __restrict__ a_res,
    float* __restrict__ scales) {
  int b = blockIdx.x;
  int t = threadIdx.x;
  __shared__ float red[4];
  __shared__ float coeff[24];
  float s = 0;
  for (int ch = 0; ch < 49; ++ch) s += pp2[((size_t)b * 49 + ch) * 256 + t];
  float pooled = s * (1.0f / (float)NPIX);
  float v = pooled * pooled;
#pragma unroll
  for (int off = 32; off; off >>= 1) v += __shfl_down(v, off);
  if ((t & 63) == 0) red[t >> 6] = v;
  __syncthreads();
  float ms = (red[0] + red[1] + red[2] + red[3]) * (1.0f / 256.0f);
  float inv = rsqrtf(ms + 1e-20f);
  __syncthreads();
  for (int o = 0; o < 24; ++o) {
    float ws_ = 0;
#pragma unroll
    for (int i = 0; i < 4; ++i) ws_ += phi_w[(size_t)o * 1024 + i * 256 + t] * rms_w[i * 256 + t];
    float c = pooled * ws_;
#pragma unroll
    for (int off = 32; off; off >>= 1) c += __shfl_down(c, off);
    if ((t & 63) == 0) red[t >> 6] = c;
    __syncthreads();
    if (t == 0) coeff[o] = inv * (red[0] + red[1] + red[2] + red[3]) + phi_b[o];
    __syncthreads();
  }
  if (t == 0) {
    float ap = a_pre[0], apo = a_post[0], ar = a_res[0];
    float spre = 0, psum = 0;
#pragma unroll
    for (int i = 0; i < 4; ++i) {
      spre += 1.0f / (1.0f + expf(-ap * coeff[i]));
      psum += 2.0f / (1.0f + expf(-apo * coeff[4 + i]));
    }
    float M[4][4];
#pragma unroll
    for (int i = 0; i < 4; ++i)
#pragma unroll
      for (int j = 0; j < 4; ++j) M[i][j] = expf(ar * coeff[8 + i * 4 + j]);
    for (int it = 0; it < 20; ++it) {
#pragma unroll
      for (int i = 0; i < 4; ++i) {
        float rs = M[i][0] + M[i][1] + M[i][2] + M[i][3];
        float rr = 1.0f / rs;
        M[i][0] *= rr; M[i][1] *= rr; M[i][2] *= rr; M[i][3] *= rr;
      }
#pragma unroll
      for (int j = 0; j < 4; ++j) {
        float cs2 = M[0][j] + M[1][j] + M[2][j] + M[3][j];
        float rr = 1.0f / cs2;
        M[0][j] *= rr; M[1][j] *= rr; M[2][j] *= rr; M[3][j] *= rr;
      }
    }
    float r = 0.25f * (M[0][0] + M[1][1] + M[2][2] + M[3][3]);
    float pm = 0.25f * psum;
    scales[b * 4 + 0] = r;          // on x
    scales[b * 4 + 1] = pm * spre;  // on conv(x)
    scales[b * 4 + 2] = pm;         // on conv_b
  }
}

// ---------------- conv implicit GEMM, 8-phase-style (m201 port):
// 512 thr / 8 waves (2M x 4N), tile 256co x 256col (cols = flattened b*3136+pix),
// BK=64 (2 (cs,tap) halves), dbuf 128 KB LDS, 4 phases/iter, counted vmcnt(4) ----------------
__global__ __launch_bounds__(512, 2) void conv_k(
    const unsigned short* __restrict__ xT, const unsigned short* __restrict__ wt,
    const float* __restrict__ x, const float* __restrict__ conv_b,
    const float* __restrict__ scales, float* __restrict__ out) {
  // buffer layout per buf: [Ak0 16K][Ak1 16K][Bk0 16K][Bk1 16K]
  __shared__ __align__(16) char lds_[2][65536];
  const int colblk = blockIdx.x;      // 392
  const int tid = threadIdx.x;
  const int wv = tid >> 6, l = tid & 63;
  const int wm = wv >> 2, wn = wv & 3;

  // ---- B staging lane addresses (2 gloads/half: 16 cols each) ----
  const char* xTbase = (const char*)xT;
  const char* laneB[2];
#pragma unroll
  for (int gi = 0; gi < 2; ++gi) {
    int col_local = wv * 32 + gi * 16 + (l >> 2);
    int col = colblk * 256 + col_local;
    int bb = col / NPIX, pix = col - bb * NPIX;
    int prow = (pix / 56 + 1) * PH + (pix % 56 + 1);
    int slot_g = (l & 3) ^ ((col_local >> 1) & 3);
    laneB[gi] = xTbase + ((size_t)bb * PPIX + prow) * 512 + slot_g * 16;
  }
  // tap -> padded-row byte shift
  const int tapsh[9] = {-59 * 512, -58 * 512, -57 * 512, -512, 0, 512, 57 * 512, 58 * 512, 59 * 512};

#define STAGE_A(STG, KS, ST) do {                                          \
    const char* s_ = (const char*)wt + (size_t)(ST) * 16384 + wv * 2048 + l * 16; \
    char* d_ = (STG) + (KS) * 16384 + wv * 2048;                           \
    gload_lds16(s_, d_); gload_lds16(s_ + 1024, d_ + 1024);                \
  } while (0)
#define STAGE_B(STG, KS, ST) do {                                          \
    int cs_ = (ST) / 9, tap_ = (ST) - cs_ * 9;                             \
    int sh_ = tapsh[tap_] + cs_ * 64;                                      \
    char* d_ = (STG) + 32768 + (KS) * 16384 + wv * 2048;                   \
    gload_lds16(laneB[0] + sh_, d_); gload_lds16(laneB[1] + sh_, d_ + 1024); \
  } while (0)

  // ---- fragment LDS byte offsets (bank-swizzled: slot ^= (row>>1)&3) ----
  int aoff[2][4], boff[4];
#pragma unroll
  for (int mh = 0; mh < 2; ++mh)
#pragma unroll
    for (int m = 0; m < 4; ++m) {
      int row = wm * 128 + mh * 64 + m * 16 + (l & 15);
      aoff[mh][m] = row * 64 + ((((l >> 4) ^ (row >> 1)) & 3) << 4);
    }
#pragma unroll
  for (int n = 0; n < 4; ++n) {
    int row = wn * 64 + n * 16 + (l & 15);
    boff[n] = row * 64 + ((((l >> 4) ^ (row >> 1)) & 3) << 4);
  }

  f32x4 acc[8][4];
#pragma unroll
  for (int m = 0; m < 8; ++m)
#pragma unroll
    for (int n = 0; n < 4; ++n) acc[m][n] = (f32x4){0.f, 0.f, 0.f, 0.f};

  // ---- prologue: stage tile 0 (stages 0,1) fully, drain, barrier ----
  STAGE_A(&lds_[0][0], 0, 0);
  STAGE_B(&lds_[0][0], 0, 0);
  STAGE_A(&lds_[0][0], 1, 1);
  STAGE_B(&lds_[0][0], 1, 1);
  asm volatile("s_waitcnt vmcnt(0)" ::: "memory");
  __builtin_amdgcn_s_barrier();

  for (int s = 0; s < 36; ++s) {
    const char* Ab = &lds_[s & 1][0];
    char* stg = &lds_[(s + 1) & 1][0];
    const int stn0 = 2 * s + 2, stn1 = 2 * s + 3;
    const bool pf = (s < 35);
    bf16x8 a0, a1, a2, a3, b0, b1, b2, b3, c0, c1, c2, c3;

    // ===== phase 0: quadrant (m-half 0, k0) =====
    a0 = *(const bf16x8*)(Ab + aoff[0][0]);
    a1 = *(const bf16x8*)(Ab + aoff[0][1]);
    a2 = *(const bf16x8*)(Ab + aoff[0][2]);
    a3 = *(const bf16x8*)(Ab + aoff[0][3]);
    b0 = *(const bf16x8*)(Ab + 32768 + boff[0]);
    b1 = *(const bf16x8*)(Ab + 32768 + boff[1]);
    b2 = *(const bf16x8*)(Ab + 32768 + boff[2]);
    b3 = *(const bf16x8*)(Ab + 32768 + boff[3]);
    if (pf) STAGE_A(stg, 0, stn0);
    __builtin_amdgcn_s_barrier();
    __builtin_amdgcn_s_setprio(1);
    acc[0][0] = __builtin_amdgcn_mfma_f32_16x16x32_bf16(a0, b0, acc[0][0], 0, 0, 0);
    acc[0][1] = __builtin_amdgcn_mfma_f32_16x16x32_bf16(a0, b1, acc[0][1], 0, 0, 0);
    acc[0][2] = __builtin_amdgcn_mfma_f32_16x16x32_bf16(a0, b2, acc[0][2], 0, 0, 0);
    acc[0][3] = __builtin_amdgcn_mfma_f32_16x16x32_bf16(a0, b3, acc[0][3], 0, 0, 0);
    acc[1][0] = __builtin_amdgcn_mfma_f32_16x16x32_bf16(a1, b0, acc[1][0], 0, 0, 0);
    acc[1][1] = __builtin_amdgcn_mfma_f32_16x16x32_bf16(a1, b1, acc[1][1], 0, 0, 0);
    acc[1][2] = __builtin_amdgcn_mfma_f32_16x16x32_bf16(a1, b2, acc[1][2], 0, 0, 0);
    acc[1][3] = __builtin_amdgcn_mfma_f32_16x16x32_bf16(a1, b3, acc[1][3], 0, 0, 0);
    acc[2][0] = __builtin_amdgcn_mfma_f32_16x16x32_bf16(a2, b0, acc[2][0], 0, 0, 0);
    acc[2][1] = __builtin_amdgcn_mfma_f32_16x16x32_bf16(a2, b1, acc[2][1], 0, 0, 0);
    acc[2][2] = __builtin_amdgcn_mfma_f32_16x16x32_bf16(a2, b2, acc[2][2], 0, 0, 0);
    acc[2][3] = __builtin_amdgcn_mfma_f32_16x16x32_bf16(a2, b3, acc[2][3], 0, 0, 0);
    acc[3][0] = __builtin_amdgcn_mfma_f32_16x16x32_bf16(a3, b0, acc[3][0], 0, 0, 0);
    acc[3][1] = __builtin_amdgcn_mfma_f32_16x16x32_bf16(a3, b1, acc[3][1], 0, 0, 0);
    acc[3][2] = __builtin_amdgcn_mfma_f32_16x16x32_bf16(a3, b2, acc[3][2], 0, 0, 0);
    acc[3][3] = __builtin_amdgcn_mfma_f32_16x16x32_bf16(a3, b3, acc[3][3], 0, 0, 0);
    __builtin_amdgcn_s_setprio(0);
    __builtin_amdgcn_s_barrier();

    // ===== phase 1: quadrant (m-half 1, k0) =====
    c0 = *(const bf16x8*)(Ab + aoff[1][0]);
    c1 = *(const bf16x8*)(Ab + aoff[1][1]);
    c2 = *(const bf16x8*)(Ab + aoff[1][2]);
    c3 = *(const bf16x8*)(Ab + aoff[1][3]);
    if (pf) STAGE_B(stg, 0, stn0);
    if (pf) { asm volatile("s_waitcnt vmcnt(4)" ::: "memory"); }
    else    { asm volatile("s_waitcnt vmcnt(0)" ::: "memory"); }
    __builtin_amdgcn_s_barrier();
    __builtin_amdgcn_s_setprio(1);
    acc[4][0] = __builtin_amdgcn_mfma_f32_16x16x32_bf16(c0, b0, acc[4][0], 0, 0, 0);
    acc[4][1] = __builtin_amdgcn_mfma_f32_16x16x32_bf16(c0, b1, acc[4][1], 0, 0, 0);
    acc[4][2] = __builtin_amdgcn_mfma_f32_16x16x32_bf16(c0, b2, acc[4][2], 0, 0, 0);
    acc[4][3] = __builtin_amdgcn_mfma_f32_16x16x32_bf16(c0, b3, acc[4][3], 0, 0, 0);
    acc[5][0] = __builtin_amdgcn_mfma_f32_16x16x32_bf16(c1, b0, acc[5][0], 0, 0, 0);
    acc[5][1] = __builtin_amdgcn_mfma_f32_16x16x32_bf16(c1, b1, acc[5][1], 0, 0, 0);
    acc[5][2] = __builtin_amdgcn_mfma_f32_16x16x32_bf16(c1, b2, acc[5][2], 0, 0, 0);
    acc[5][3] = __builtin_amdgcn_mfma_f32_16x16x32_bf16(c1, b3, acc[5][3], 0, 0, 0);
    acc[6][0] = __builtin_amdgcn_mfma_f32_16x16x32_bf16(c2, b0, acc[6][0], 0, 0, 0);
    acc[6][1] = __builtin_amdgcn_mfma_f32_16x16x32_bf16(c2, b1, acc[6][1], 0, 0, 0);
    acc[6][2] = __builtin_amdgcn_mfma_f32_16x16x32_bf16(c2, b2, acc[6][2], 0, 0, 0);
    acc[6][3] = __builtin_amdgcn_mfma_f32_16x16x32_bf16(c2, b3, acc[6][3], 0, 0, 0);
    acc[7][0] = __builtin_amdgcn_mfma_f32_16x16x32_bf16(c3, b0, acc[7][0], 0, 0, 0);
    acc[7][1] = __builtin_amdgcn_mfma_f32_16x16x32_bf16(c3, b1, acc[7][1], 0, 0, 0);
    acc[7][2] = __builtin_amdgcn_mfma_f32_16x16x32_bf16(c3, b2, acc[7][2], 0, 0, 0);
    acc[7][3] = __builtin_amdgcn_mfma_f32_16x16x32_bf16(c3, b3, acc[7][3], 0, 0, 0);
    __builtin_amdgcn_s_setprio(0);
    __builtin_amdgcn_s_barrier();

    // ===== phase 2: quadrant (m-half 0, k1) =====
    a0 = *(const bf16x8*)(Ab + 16384 + aoff[0][0]);
    a1 = *(const bf16x8*)(Ab + 16384 + aoff[0][1]);
    a2 = *(const bf16x8*)(Ab + 16384 + aoff[0][2]);
    a3 = *(const bf16x8*)(Ab + 16384 + aoff[0][3]);
    b0 = *(const bf16x8*)(Ab + 49152 + boff[0]);
    b1 = *(const bf16x8*)(Ab + 49152 + boff[1]);
    b2 = *(const bf16x8*)(Ab + 49152 + boff[2]);
    b3 = *(const bf16x8*)(Ab + 49152 + boff[3]);
    if (pf) STAGE_A(stg, 1, stn1);
    __builtin_amdgcn_s_barrier();
    __builtin_amdgcn_s_setprio(1);
    acc[0][0] = __builtin_amdgcn_mfma_f32_16x16x32_bf16(a0, b0, acc[0][0], 0, 0, 0);
    acc[0][1] = __builtin_amdgcn_mfma_f32_16x16x32_bf16(a0, b1, acc[0][1], 0, 0, 0);
    acc[0][2] = __builtin_amdgcn_mfma_f32_16x16x32_bf16(a0, b2, acc[0][2], 0, 0, 0);
    acc[0][3] = __builtin_amdgcn_mfma_f32_16x16x32_bf16(a0, b3, acc[0][3], 0, 0, 0);
    acc[1][0] = __builtin_amdgcn_mfma_f32_16x16x32_bf16(a1, b0, acc[1][0], 0, 0, 0);
    acc[1][1] = __builtin_amdgcn_mfma_f32_16x16x32_bf16(a1, b1, acc[1][1], 0, 0, 0);
    acc[1][2] = __builtin_amdgcn_mfma_f32_16x16x32_bf16(a1, b2, acc[1][2], 0, 0, 0);
    acc[1][3] = __builtin_amdgcn_mfma_f32_16x16x32_bf16(a1, b3, acc[1][3], 0, 0, 0);
    acc[2][0] = __builtin_amdgcn_mfma_f32_16x16x32_bf16(a2, b0, acc[2][0], 0, 0, 0);
    acc[2][1] = __builtin_amdgcn_mfma_f32_16x16x32_bf16(a2, b1, acc[2][1], 0, 0, 0);
    acc[2][2] = __builtin_amdgcn_mfma_f32_16x16x32_bf16(a2, b2, acc[2][2], 0, 0, 0);
    acc[2][3] = __builtin_amdgcn_mfma_f32_16x16x32_bf16(a2, b3, acc[2][3], 0, 0, 0);
    acc[3][0] = __builtin_amdgcn_mfma_f32_16x16x32_bf16(a3, b0, acc[3][0], 0, 0, 0);
    acc[3][1] = __builtin_amdgcn_mfma_f32_16x16x32_bf16(a3, b1, acc[3][1], 0, 0, 0);
    acc[3][2] = __builtin_amdgcn_mfma_f32_16x16x32_bf16(a3, b2, acc[3][2], 0, 0, 0);
    acc[3][3] = __builtin_amdgcn_mfma_f32_16x16x32_bf16(a3, b3, acc[3][3], 0, 0, 0);
    __builtin_amdgcn_s_setprio(0);
    __builtin_amdgcn_s_barrier();

    // ===== phase 3: quadrant (m-half 1, k1) =====
    c0 = *(const bf16x8*)(Ab + 16384 + aoff[1][0]);
    c1 = *(const bf16x8*)(Ab + 16384 + aoff[1][1]);
    c2 = *(const bf16x8*)(Ab + 16384 + aoff[1][2]);
    c3 = *(const bf16x8*)(Ab + 16384 + aoff[1][3]);
    if (pf) {
      STAGE_B(stg, 1, stn1);
      asm volatile("s_waitcnt vmcnt(4)" ::: "memory");
    }
    __builtin_amdgcn_s_barrier();
    __builtin_amdgcn_s_setprio(1);
    acc[4][0] = __builtin_amdgcn_mfma_f32_16x16x32_bf16(c0, b0, acc[4][0], 0, 0, 0);
    acc[4][1] = __builtin_amdgcn_mfma_f32_16x16x32_bf16(c0, b1, acc[4][1], 0, 0, 0);
    acc[4][2] = __builtin_amdgcn_mfma_f32_16x16x32_bf16(c0, b2, acc[4][2], 0, 0, 0);
    acc[4][3] = __builtin_amdgcn_mfma_f32_16x16x32_bf16(c0, b3, acc[4][3], 0, 0, 0);
    acc[5][0] = __builtin_amdgcn_mfma_f32_16x16x32_bf16(c1, b0, acc[5][0], 0, 0, 0);
    acc[5][1] = __builtin_amdgcn_mfma_f32_16x16x32_bf16(c1, b1, acc[5][1], 0, 0, 0);
    acc[5][2] = __builtin_amdgcn_mfma_f32_16x16x32_bf16(c1, b2, acc[5][2], 0, 0, 0);
    acc[5][3] = __builtin_amdgcn_mfma_f32_16x16x32_bf16(c1, b3, acc[5][3], 0, 0, 0);
    acc[6][0] = __builtin_amdgcn_mfma_f32_16x16x32_bf16(c2, b0, acc[6][0], 0, 0, 0);
    acc[6][1] = __builtin_amdgcn_mfma_f32_16x16x32_bf16(c2, b1, acc[6][1], 0, 0, 0);
    acc[6][2] = __builtin_amdgcn_mfma_f32_16x16x32_bf16(c2, b2, acc[6][2], 0, 0, 0);
    acc[6][3] = __builtin_amdgcn_mfma_f32_16x16x32_bf16(c2, b3, acc[6][3], 0, 0, 0);
    acc[7][0] = __builtin_amdgcn_mfma_f32_16x16x32_bf16(c3, b0, acc[7][0], 0, 0, 0);
    acc[7][1] = __builtin_amdgcn_mfma_f32_16x16x32_bf16(c3, b1, acc[7][1], 0, 0, 0);
    acc[7][2] = __builtin_amdgcn_mfma_f32_16x16x32_bf16(c3, b2, acc[7][2], 0, 0, 0);
    acc[7][3] = __builtin_amdgcn_mfma_f32_16x16x32_bf16(c3, b3, acc[7][3], 0, 0, 0);
    __builtin_amdgcn_s_setprio(0);
    __builtin_amdgcn_s_barrier();
  }
#undef STAGE_A
#undef STAGE_B

  // ---- epilogue: out = sX*x + sY*conv + sB*conv_b ----
  const int lc = l & 15, lg = l >> 4;
  float sXn[4], sYn[4], sBn[4];
  size_t obase[4];
#pragma unroll
  for (int n = 0; n < 4; ++n) {
    int col = colblk * 256 + wn * 64 + n * 16 + lc;
    int bb = col / NPIX, pix = col - bb * NPIX;
    sXn[n] = scales[bb * 4 + 0];
    sYn[n] = scales[bb * 4 + 1];
    sBn[n] = scales[bb * 4 + 2];
    obase[n] = (size_t)bb * NCH * NPIX + pix;
  }
#pragma unroll
  for (int m = 0; m < 8; ++m) {
#pragma unroll
    for (int j = 0; j < 4; ++j) {
      int co = wm * 128 + m * 16 + lg * 4 + j;
      float cbv = conv_b[co];
      size_t cooff = (size_t)co * NPIX;
#pragma unroll
      for (int n = 0; n < 4; ++n) {
        size_t idx = obase[n] + cooff;
        out[idx] = sXn[n] * x[idx] + sYn[n] * acc[m][n][j] + sBn[n] * cbv;
      }
    }
  }
}

extern "C" void kernel_launch(void* const* d_in, const int* in_sizes, int n_in,
                              void* d_out, int out_size, void* d_ws, size_t ws_size,
                              hipStream_t stream) {
  const float* x      = (const float*)d_in[0];
  const float* phi_w  = (const float*)d_in[1];
  const float* phi_b  = (const float*)d_in[2];
  const float* rms_w  = (const float*)d_in[3];
  const float* a_pre  = (const float*)d_in[4];
  const float* a_post = (const float*)d_in[5];
  const float* a_res  = (const float*)d_in[6];
  const float* conv_w = (const float*)d_in[7];
  const float* conv_b = (const float*)d_in[8];
  float* out = (float*)d_out;

  char* ws = (char*)d_ws;
  unsigned short* xT = (unsigned short*)ws;
  const size_t XT_BYTES = (size_t)NB * PPIX * NCH * 2;            // 55,115,776
  float* pp2 = (float*)(ws + XT_BYTES);
  const size_t PP_BYTES = (size_t)NB * 49 * 256 * 4;              // 1,605,632
  float* scales = (float*)(ws + XT_BYTES + PP_BYTES);
  unsigned short* wt = (unsigned short*)(ws + XT_BYTES + PP_BYTES + 512);

  prep_k<<<dim3(144 + 3648), dim3(256), 0, stream>>>(conv_w, wt, xT);
  transpose_x<<<dim3(49, 4, NB), dim3(256), 0, stream>>>(x, xT, pp2);
  head_k<<<dim3(NB), dim3(256), 0, stream>>>(pp2, phi_w, phi_b, rms_w, a_pre, a_post, a_res, scales);
  conv_k<<<dim3(392), dim3(512), 0, stream>>>(xT, wt, x, conv_b, scales, out);
}